// Round 1
// baseline (921.491 us; speedup 1.0000x reference)
//
#include <hip/hip_runtime.h>
#include <stdint.h>

#define NB 32768      // batch
#define HH 1024       // hidden (cell)
#define PP 128        // proj size
#define INW 263       // input width
#define K0P 448       // padded K for layer0 gates (263+128 -> 448)
#define K1P 256       // K for layer1 gates (128+128)
#define G4H 4096      // 4*H

typedef __attribute__((ext_vector_type(8))) short short8;
typedef __attribute__((ext_vector_type(4))) float floatx4;

__device__ __forceinline__ unsigned short f2bf(float x) {
    union { float f; unsigned int u; } v; v.f = x;
    unsigned int r = v.u + 0x7fffu + ((v.u >> 16) & 1u);
    return (unsigned short)(r >> 16);
}
__device__ __forceinline__ float sigm(float x) { return 1.f / (1.f + __expf(-x)); }
__device__ __forceinline__ float tanhfast(float x) { return 2.f / (1.f + __expf(-2.f * x)) - 1.f; }

__device__ __forceinline__ void load_lds16(const void* g, void* l) {
    __builtin_amdgcn_global_load_lds((const __attribute__((address_space(1))) void*)g,
                                     (__attribute__((address_space(3))) void*)l,
                                     16, 0, 0);
}

// ---------------- prep: inputs -> bf16 packed (Xcat0 [N,448], Xcat1 hidden half [N,256]) ------
__global__ void prep_inputs(const float* __restrict__ inp, const float* __restrict__ hl,
                            unsigned short* __restrict__ X0, unsigned short* __restrict__ X1) {
    const int T0 = NB * K0P;
    const int T1 = T0 + NB * PP;
    for (int idx = blockIdx.x * 256 + threadIdx.x; idx < T1; idx += gridDim.x * 256) {
        if (idx < T0) {
            int n = idx / K0P, c = idx - n * K0P;
            float v = 0.f;
            if (c < INW) v = inp[n * INW + c];
            else if (c < INW + PP) v = hl[n * PP + (c - INW)];
            X0[idx] = f2bf(v);
        } else {
            int k = idx - T0;
            int n = k >> 7, c = k & 127;
            X1[n * K1P + PP + c] = f2bf(hl[NB * PP + k]);
        }
    }
}

// ---------------- prep: weights (permute rows so each col-block's 128 B-rows are contiguous) ---
// Wperm row index = cb*128 + t,  src_row = (t>>5)*1024 + cb*32 + (t&31)   (gate=t>>5)
__global__ void prep_weights(const float* __restrict__ Wih0, const float* __restrict__ Whh0,
                             const float* __restrict__ Wih1, const float* __restrict__ Whh1,
                             const float* __restrict__ Whr0, const float* __restrict__ Whr1,
                             const float* __restrict__ bih0, const float* __restrict__ bhh0,
                             const float* __restrict__ bih1, const float* __restrict__ bhh1,
                             unsigned short* __restrict__ Wp0, unsigned short* __restrict__ Wp1,
                             unsigned short* __restrict__ Whr0b, unsigned short* __restrict__ Whr1b,
                             float* __restrict__ b0, float* __restrict__ b1) {
    const int T0 = G4H * K0P;
    const int T1 = T0 + G4H * K1P;
    const int T2 = T1 + PP * HH;
    const int T3 = T2 + PP * HH;
    const int T4 = T3 + G4H;
    const int T5 = T4 + G4H;
    for (int idx = blockIdx.x * 256 + threadIdx.x; idx < T5; idx += gridDim.x * 256) {
        if (idx < T0) {
            int r = idx / K0P, c = idx - r * K0P;
            int cbb = r >> 7, tt = r & 127;
            int src = (tt >> 5) * 1024 + cbb * 32 + (tt & 31);
            float v = 0.f;
            if (c < INW) v = Wih0[src * INW + c];
            else if (c < INW + PP) v = Whh0[src * PP + (c - INW)];
            Wp0[idx] = f2bf(v);
        } else if (idx < T1) {
            int k = idx - T0;
            int r = k >> 8, c = k & 255;
            int cbb = r >> 7, tt = r & 127;
            int src = (tt >> 5) * 1024 + cbb * 32 + (tt & 31);
            float v = (c < PP) ? Wih1[src * PP + c] : Whh1[src * PP + (c - PP)];
            Wp1[k] = f2bf(v);
        } else if (idx < T2) {
            int k = idx - T1; Whr0b[k] = f2bf(Whr0[k]);
        } else if (idx < T3) {
            int k = idx - T2; Whr1b[k] = f2bf(Whr1[k]);
        } else if (idx < T4) {
            int k = idx - T3; b0[k] = bih0[k] + bhh0[k];
        } else {
            int k = idx - T4; b1[k] = bih1[k] + bhh1[k];
        }
    }
}

// ---------------- gates GEMM + fused LSTM cell elementwise -------------------------------------
// C[row, tcol] = sum_k A[row,k] * Wperm[cb*128+tcol, k];  tcol = gate*32 + u (u: hidden-in-block)
// wave w: rows w*32..w*32+31 x all 128 cols. acc[mi][ci]: ci = gate*2 + (u>>4).
template<int KPAD>
__global__ __launch_bounds__(256, 2) void gemm_gates_k(
    const unsigned short* __restrict__ A,   // [NB, KPAD] bf16 bits
    const unsigned short* __restrict__ Bp,  // [4096, KPAD] permuted bf16 bits
    const float* __restrict__ bias,         // [4096] i|f|g|o
    const float* __restrict__ c_prev,       // [NB, 1024]
    float* __restrict__ c_out,              // [NB, 1024] (d_out cn slice)
    unsigned short* __restrict__ tmp_out)   // [NB, 1024] bf16 = sigmoid(o)*tanh(c_new)
{
    __shared__ unsigned short As[128 * 64];
    __shared__ unsigned short Bs[128 * 64];
    const int t  = threadIdx.x;
    const int w  = t >> 6;
    const int l  = t & 63;
    const int lc = l & 15;
    const int q4 = l >> 4;
    const int cb = blockIdx.x;   // 0..31 (fast dim: 32 col-blocks share the A tile -> L2 reuse)
    const int mb = blockIdx.y;   // 0..255

    floatx4 acc[2][8];
#pragma unroll
    for (int i = 0; i < 2; ++i)
#pragma unroll
        for (int j = 0; j < 8; ++j) acc[i][j] = (floatx4){0.f, 0.f, 0.f, 0.f};

    const int arow = t >> 3;                       // 0..31
    const int sw   = ((t & 7) ^ ((t >> 3) & 7)) * 8; // XOR-swizzled k-chunk (bank-conflict fix)
    const unsigned short* gA = A  + (size_t)(mb * 128 + arow) * KPAD + sw;
    const unsigned short* gB = Bp + (size_t)(cb * 128 + arow) * KPAD + sw;
    char* ldsA = (char*)As + t * 16;
    char* ldsB = (char*)Bs + t * 16;

    for (int kt = 0; kt < KPAD; kt += 64) {
#pragma unroll
        for (int i = 0; i < 4; ++i) {
            load_lds16(gA + (size_t)(i * 32) * KPAD + kt, ldsA + i * 4096);
            load_lds16(gB + (size_t)(i * 32) * KPAD + kt, ldsB + i * 4096);
        }
        __syncthreads();
        const short* Asp = (const short*)As;
        const short* Bsp = (const short*)Bs;
#pragma unroll
        for (int kc = 0; kc < 2; ++kc) {
            const int kchunk = kc * 4 + q4;
            const int rsw = (kchunk ^ (lc & 7)) * 8;
            short8 a[2];
#pragma unroll
            for (int mi = 0; mi < 2; ++mi)
                a[mi] = *(const short8*)&Asp[(w * 32 + mi * 16 + lc) * 64 + rsw];
#pragma unroll
            for (int ci = 0; ci < 8; ++ci) {
                short8 b = *(const short8*)&Bsp[(ci * 16 + lc) * 64 + rsw];
#pragma unroll
                for (int mi = 0; mi < 2; ++mi)
                    acc[mi][ci] = __builtin_amdgcn_mfma_f32_16x16x32_bf16(a[mi], b, acc[mi][ci], 0, 0, 0);
            }
        }
        __syncthreads();
    }

    // fused LSTM cell epilogue: lane holds i,f,g,o for hidden u = u4*16+lc at rows q4*4+r
#pragma unroll
    for (int u4 = 0; u4 < 2; ++u4) {
        const int hidx = cb * 32 + u4 * 16 + lc;
        const float bi = bias[hidx];
        const float bf = bias[1024 + hidx];
        const float bg = bias[2048 + hidx];
        const float bo = bias[3072 + hidx];
#pragma unroll
        for (int mi = 0; mi < 2; ++mi) {
#pragma unroll
            for (int r = 0; r < 4; ++r) {
                const int row = mb * 128 + w * 32 + mi * 16 + q4 * 4 + r;
                const float iv = acc[mi][0 + u4][r] + bi;
                const float fv = acc[mi][2 + u4][r] + bf;
                const float gv = acc[mi][4 + u4][r] + bg;
                const float ov = acc[mi][6 + u4][r] + bo;
                const float cp = c_prev[(size_t)row * 1024 + hidx];
                const float cn = sigm(fv) * cp + sigm(iv) * tanhfast(gv);
                c_out[(size_t)row * 1024 + hidx] = cn;
                tmp_out[(size_t)row * 1024 + hidx] = f2bf(sigm(ov) * tanhfast(cn));
            }
        }
    }
}

// ---------------- projection GEMM: h = tmp @ Whr^T  (K=1024, 128 out cols) ---------------------
__global__ __launch_bounds__(256, 2) void gemm_proj_k(
    const unsigned short* __restrict__ A,   // [NB, 1024] bf16 bits
    const unsigned short* __restrict__ B,   // [128, 1024] bf16 bits
    float* __restrict__ hout,               // [NB, 128] (d_out hn slice)
    unsigned short* __restrict__ xc1)       // [NB, 256] cols 0..127 (layer1 input) or null
{
    __shared__ unsigned short As[128 * 64];
    __shared__ unsigned short Bs[128 * 64];
    const int t  = threadIdx.x;
    const int w  = t >> 6;
    const int l  = t & 63;
    const int lc = l & 15;
    const int q4 = l >> 4;
    const int mb = blockIdx.x;   // 0..255

    floatx4 acc[2][8];
#pragma unroll
    for (int i = 0; i < 2; ++i)
#pragma unroll
        for (int j = 0; j < 8; ++j) acc[i][j] = (floatx4){0.f, 0.f, 0.f, 0.f};

    const int arow = t >> 3;
    const int sw   = ((t & 7) ^ ((t >> 3) & 7)) * 8;
    const unsigned short* gA = A + (size_t)(mb * 128 + arow) * 1024 + sw;
    const unsigned short* gB = B + (size_t)arow * 1024 + sw;
    char* ldsA = (char*)As + t * 16;
    char* ldsB = (char*)Bs + t * 16;

    for (int kt = 0; kt < 1024; kt += 64) {
#pragma unroll
        for (int i = 0; i < 4; ++i) {
            load_lds16(gA + (size_t)(i * 32) * 1024 + kt, ldsA + i * 4096);
            load_lds16(gB + (size_t)(i * 32) * 1024 + kt, ldsB + i * 4096);
        }
        __syncthreads();
        const short* Asp = (const short*)As;
        const short* Bsp = (const short*)Bs;
#pragma unroll
        for (int kc = 0; kc < 2; ++kc) {
            const int kchunk = kc * 4 + q4;
            const int rsw = (kchunk ^ (lc & 7)) * 8;
            short8 a[2];
#pragma unroll
            for (int mi = 0; mi < 2; ++mi)
                a[mi] = *(const short8*)&Asp[(w * 32 + mi * 16 + lc) * 64 + rsw];
#pragma unroll
            for (int ci = 0; ci < 8; ++ci) {
                short8 b = *(const short8*)&Bsp[(ci * 16 + lc) * 64 + rsw];
#pragma unroll
                for (int mi = 0; mi < 2; ++mi)
                    acc[mi][ci] = __builtin_amdgcn_mfma_f32_16x16x32_bf16(a[mi], b, acc[mi][ci], 0, 0, 0);
            }
        }
        __syncthreads();
    }

#pragma unroll
    for (int ci = 0; ci < 8; ++ci) {
        const int col = ci * 16 + lc;
#pragma unroll
        for (int mi = 0; mi < 2; ++mi) {
#pragma unroll
            for (int r = 0; r < 4; ++r) {
                const int row = mb * 128 + w * 32 + mi * 16 + q4 * 4 + r;
                const float v = acc[mi][ci][r];
                hout[(size_t)row * 128 + col] = v;
                if (xc1) xc1[(size_t)row * K1P + col] = f2bf(v);
            }
        }
    }
}

// ---------------- softmax(h1 + prior) over 128 cols --------------------------------------------
__global__ void softmax_k(const float* __restrict__ h1, const int* __restrict__ clp,
                          float* __restrict__ out) {
    const int w = threadIdx.x >> 6, l = threadIdx.x & 63;
    const int row = blockIdx.x * 4 + w;
    const int cl = clp[0];
    float pd = 0.f;
    // prior[0:32] if cl<64 ; prior[96:128] if cl>64
    float d = (float)(64 - cl);
    float pv = -(d * d) * (1.f / 16.f);
    float p0 = (cl < 64 && l < 32) ? pv : 0.f;
    float p1 = (cl > 64 && (l + 64) >= 96) ? pv : 0.f;
    (void)pd;
    float v0 = h1[(size_t)row * 128 + l] + p0;
    float v1 = h1[(size_t)row * 128 + 64 + l] + p1;
    float m = fmaxf(v0, v1);
#pragma unroll
    for (int off = 32; off > 0; off >>= 1) m = fmaxf(m, __shfl_xor(m, off, 64));
    float e0 = __expf(v0 - m), e1 = __expf(v1 - m);
    float s = e0 + e1;
#pragma unroll
    for (int off = 32; off > 0; off >>= 1) s += __shfl_xor(s, off, 64);
    float inv = 1.f / s;
    out[(size_t)row * 128 + l] = e0 * inv;
    out[(size_t)row * 128 + 64 + l] = e1 * inv;
}

extern "C" void kernel_launch(void* const* d_in, const int* in_sizes, int n_in,
                              void* d_out, int out_size, void* d_ws, size_t ws_size,
                              hipStream_t stream) {
    const float* input = (const float*)d_in[0];
    const float* hidden = (const float*)d_in[1];    // c-state [2,N,1024]
    const float* hlstm  = (const float*)d_in[2];    // h-state [2,N,128]
    const float* Wih0 = (const float*)d_in[3];
    const float* Whh0 = (const float*)d_in[4];
    const float* bih0 = (const float*)d_in[5];
    const float* bhh0 = (const float*)d_in[6];
    const float* Whr0 = (const float*)d_in[7];
    const float* Wih1 = (const float*)d_in[8];
    const float* Whh1 = (const float*)d_in[9];
    const float* bih1 = (const float*)d_in[10];
    const float* bhh1 = (const float*)d_in[11];
    const float* Whr1 = (const float*)d_in[12];
    const int* curlen = (const int*)d_in[13];

    float* out = (float*)d_out;                         // [N,128]
    float* cn0 = out + (size_t)NB * PP;                 // [N,1024]
    float* cn1 = cn0 + (size_t)NB * HH;                 // [N,1024]
    float* hn0 = cn1 + (size_t)NB * HH;                 // [N,128]
    float* hn1 = hn0 + (size_t)NB * PP;                 // [N,128]

    char* p = (char*)d_ws;
    unsigned short* X0    = (unsigned short*)p; p += (size_t)NB * K0P * 2;
    unsigned short* X1    = (unsigned short*)p; p += (size_t)NB * K1P * 2;
    unsigned short* Wp0   = (unsigned short*)p; p += (size_t)G4H * K0P * 2;
    unsigned short* Wp1   = (unsigned short*)p; p += (size_t)G4H * K1P * 2;
    unsigned short* Whr0b = (unsigned short*)p; p += (size_t)PP * HH * 2;
    unsigned short* Whr1b = (unsigned short*)p; p += (size_t)PP * HH * 2;
    float* b0 = (float*)p; p += (size_t)G4H * 4;
    float* b1 = (float*)p; p += (size_t)G4H * 4;
    unsigned short* tmp0 = (unsigned short*)p; p += (size_t)NB * HH * 2;
    unsigned short* tmp1 = (unsigned short*)p; p += (size_t)NB * HH * 2;

    prep_inputs<<<8192, 256, 0, stream>>>(input, hlstm, X0, X1);
    prep_weights<<<4096, 256, 0, stream>>>(Wih0, Whh0, Wih1, Whh1, Whr0, Whr1,
                                           bih0, bhh0, bih1, bhh1,
                                           Wp0, Wp1, Whr0b, Whr1b, b0, b1);
    gemm_gates_k<K0P><<<dim3(32, 256), 256, 0, stream>>>(X0, Wp0, b0, hidden, cn0, tmp0);
    gemm_proj_k<<<256, 256, 0, stream>>>(tmp0, Whr0b, hn0, X1);
    gemm_gates_k<K1P><<<dim3(32, 256), 256, 0, stream>>>(X1, Wp1, b1, hidden + (size_t)NB * HH, cn1, tmp1);
    gemm_proj_k<<<256, 256, 0, stream>>>(tmp1, Whr1b, hn1, nullptr);
    softmax_k<<<NB / 4, 256, 0, stream>>>(hn1, curlen, out);
}